// Round 7
// baseline (283.433 us; speedup 1.0000x reference)
//
#include <hip/hip_runtime.h>

#define INSZ   2048
#define NH1    256
#define NH2    64
#define NB     8
#define BATCH  16384

#define TS        64                 // rows per block-tile
#define MAXTILES  (BATCH / TS)       // 256 (worst case: all samples in one bucket)
#define GRIDX     (NB * MAXTILES)    // 2048, bkt = blockIdx & 7 -> XCD pin heuristic

// W1f: [bkt][kb(64)][cb(16)][lane(64)][8] bf16
#define W1F_U4   (NB * 64 * 16 * 64)        // 524288 uint4
#define W2F_U4   (NB * 8 * 4 * 64)          // 16384 uint4

// ws layout (bytes)
#define META_OFF  0                  // 32 ints: cnt[8], off[8], cursor[8]
#define ORDER_OFF 1024               // 16384 ints
#define W1F_OFF   (1024 + BATCH * 4)            // 66560
#define W2F_OFF   (W1F_OFF + W1F_U4 * 16)       // 8,455,168
#define WS_NEED   (W2F_OFF + W2F_U4 * 16)       // 8,717,312

typedef float f4  __attribute__((ext_vector_type(4)));
typedef float f32x4 __attribute__((ext_vector_type(4)));
typedef short bf16x8 __attribute__((ext_vector_type(8)));

__device__ __forceinline__ unsigned short f2bf(float f) {
    unsigned u = __float_as_uint(f);
    u += 0x7fffu + ((u >> 16) & 1u);   // RNE
    return (unsigned short)(u >> 16);
}
__device__ __forceinline__ float clamp01(float v) { return fminf(fmaxf(v, 0.0f), 1.0f); }
__device__ __forceinline__ unsigned pack2(float a, float b) {
    return (unsigned)f2bf(a) | ((unsigned)f2bf(b) << 16);
}

// ============================ pre-pass kernels ============================

__global__ void k_countscan(const int* __restrict__ idx, int* __restrict__ meta) {
    __shared__ int scnt[NB];
    int t = threadIdx.x;
    if (t < NB) scnt[t] = 0;
    __syncthreads();
    int local[NB];
#pragma unroll
    for (int bb = 0; bb < NB; bb++) local[bb] = 0;
    for (int i = t; i < BATCH; i += 1024) {
        int b = idx[i];
#pragma unroll
        for (int bb = 0; bb < NB; bb++) local[bb] += (b == bb) ? 1 : 0;
    }
#pragma unroll
    for (int bb = 0; bb < NB; bb++) {
        int v = local[bb];
        v += __shfl_xor(v, 1);  v += __shfl_xor(v, 2);  v += __shfl_xor(v, 4);
        v += __shfl_xor(v, 8);  v += __shfl_xor(v, 16); v += __shfl_xor(v, 32);
        if ((t & 63) == 0) atomicAdd(&scnt[bb], v);
    }
    __syncthreads();
    if (t == 0) {
        int run = 0;
        for (int b = 0; b < NB; b++) {
            int c = scnt[b];
            meta[b]      = c;
            meta[8 + b]  = run;
            meta[16 + b] = run;   // scatter cursor
            run += c;
        }
    }
}

__global__ void k_scatter(const int* __restrict__ idx, int* __restrict__ meta,
                          int* __restrict__ order) {
    __shared__ int wcnt[16][NB];
    __shared__ int sbase[NB];
    int t = threadIdx.x;
    int i = blockIdx.x * 1024 + t;
    int b = idx[i];
    int wv = t >> 6, lane = t & 63;
    unsigned long long mymask = 0;
#pragma unroll
    for (int bb = 0; bb < NB; bb++) {
        unsigned long long m = __ballot(b == bb);
        if (b == bb) mymask = m;
        if (lane == bb) wcnt[wv][bb] = (int)__popcll(m);
    }
    int myrank = (int)__popcll(mymask & ((1ull << lane) - 1ull));
    __syncthreads();
    if (t < NB) {
        int sum = 0;
        for (int w2 = 0; w2 < 16; w2++) { int c = wcnt[w2][t]; wcnt[w2][t] = sum; sum += c; }
        sbase[t] = atomicAdd(&meta[16 + t], sum);
    }
    __syncthreads();
    order[sbase[b] + wcnt[wv][b] + myrank] = i;
}

// pack W1/W2 into per-lane MFMA B-fragment order (bf16).
// v11: read-side remapped so consecutive threads read CONSECUTIVE 32B of W
// (coalesced); writes scatter instead (stores are cheap). Output layout
// identical to before: W1f[bkt][kb][cb][lane=quad*16+l15][8].
__global__ void k_pack(const float* __restrict__ W1, const float* __restrict__ W2,
                       uint4* __restrict__ W1f, uint4* __restrict__ W2f) {
    int u = blockIdx.x * 256 + threadIdx.x;
    if (u < W1F_U4) {
        // u = [bkt(3)][row(8)][k8(8)] ; row-major coalesced read of 8 floats
        int k8 = u & 255, row = (u >> 8) & 255, bkt = u >> 16;
        int kb = k8 >> 2, quad = k8 & 3;
        int cb = row >> 4, l15 = row & 15;
        const float* p = W1 + ((size_t)(bkt * NH1 + row)) * INSZ + k8 * 8;
        f4 lo = *(const f4*)p, hi = *(const f4*)(p + 4);
        uint4 o;
        o.x = pack2(lo[0], lo[1]); o.y = pack2(lo[2], lo[3]);
        o.z = pack2(hi[0], hi[1]); o.w = pack2(hi[2], hi[3]);
        W1f[((bkt * 64 + kb) * 16 + cb) * 64 + quad * 16 + l15] = o;
    } else {
        int v = u - W1F_U4;
        if (v >= W2F_U4) return;
        // v = [bkt(3)][row(6)][k8(5)]
        int k8 = v & 31, row = (v >> 5) & 63, bkt = v >> 11;
        int kb2 = k8 >> 2, quad = k8 & 3;
        int cg2 = row >> 4, l15 = row & 15;
        const float* p = W2 + ((size_t)(bkt * NH2 + row)) * NH1 + k8 * 8;
        f4 lo = *(const f4*)p, hi = *(const f4*)(p + 4);
        uint4 o;
        o.x = pack2(lo[0], lo[1]); o.y = pack2(lo[2], lo[3]);
        o.z = pack2(hi[0], hi[1]); o.w = pack2(hi[2], hi[3]);
        W2f[((bkt * 8 + kb2) * 4 + cg2) * 64 + quad * 16 + l15] = o;
    }
}

// ============================ main fused kernel ============================
// v11: CHUNKED staging — 8 K-steps per barrier instead of 1.
// Four rounds of evidence (v6-v10) isolated the pacer as the per-K-step
// barrier itself (~3000cy/step vs ~400cy of work, invariant under prefetch
// depth, clobber hygiene, and 2-blocks/CU occupancy). v11 stages x for 8
// K-steps at a time into a double-buffered 40KB LDS region (8 step-slices,
// each the proven [64][40]-stride layout), giving 9 __syncthreads() total.
// Between barriers: ~500 instructions of ds_read/W-load/MFMA with NO sync —
// the compiler-schedulable regime. Barrier drains are free: the x loads
// drained at a chunk's end were issued a full chunk (~2000cy) earlier.
// sh1/sPart alias the dead staging buffers -> LDS = 80KB -> 2 blocks/CU.
//
// Per wave per step: 4 A-frags (ds_read_b128) x 2 B-frags (global, L2-hot,
// wave-private cols w*32..+31) = 8 MFMA. x staging: thread t -> row t>>3,
// slice kq=t&7, 32 consecutive floats (8x f4, coalesced 1KB/row).
//
// (Third submission of this experiment: rounds 5 and 6 both died on
// GPU-broker infrastructure — container spin-up failure, then acquisition
// timeout — with no kernel verdict. Source audited r5: uniform barriers,
// 80KB LDS = 2 blocks/CU, packer algebra verified both directions, no
// device-side alloc/sync.)

__global__ __launch_bounds__(512, 4) void fused_v11(
    const float* __restrict__ x, const int* __restrict__ meta,
    const int* __restrict__ order,
    const short* __restrict__ W1f, const short* __restrict__ W2f,
    const float* __restrict__ b1, const float* __restrict__ b2,
    const float* __restrict__ W3, const float* __restrict__ b3,
    float* __restrict__ out)
{
    const int bkt  = blockIdx.x & 7;
    const int tile = blockIdx.x >> 3;     // identity: actives = first ~256 blocks
    const int cnt  = meta[bkt];
    const int base = tile * TS;
    if (base >= cnt) return;
    const int off = meta[8 + bkt];

    // 2 x 20480 shorts: chunk buffers [8 slices][64 rows][40 shorts].
    // After the K-loop: sh1 (16896 shorts, stride 264) aliases buffer 0,
    // sPart (128 floats) aliases buffer 1.
    __shared__ short smem[40960];
    short* sX0 = smem;
    short* sX1 = smem + 20480;
    short* sh1 = smem;
    float* sPart = (float*)(smem + 20480);

    const int t = threadIdx.x;
    const int lane = t & 63, w = t >> 6;
    const int l15 = lane & 15, quad = lane >> 4;

    // x staging: thread t -> row t>>3, slice kq = t&7 (32 consecutive floats)
    const int xr = t >> 3, kq = t & 7;
    int ir = base + xr; if (ir > cnt - 1) ir = cnt - 1;
    const float* xtp = x + (size_t)order[off + ir] * INSZ + kq * 32;
    const int sxo = kq * 2560 + xr * 40;          // slice base + row (shorts)

    // per-wave W1 fragment pointer: frag (kb, cb=2w+j) at kb*8192 + j*512 (+lane*8)
    const short* wp = W1f + ((size_t)bkt << 19) + (size_t)(2 * w) * 512 + lane * 8;

    f32x4 acc[4][2];
#pragma unroll
    for (int f = 0; f < 4; f++)
#pragma unroll
        for (int j = 0; j < 2; j++) acc[f][j] = (f32x4)0.0f;

    // ---- prologue: stage chunk 0 into sX0 ----
    {
        f4 xl[8];
#pragma unroll
        for (int q = 0; q < 8; q++) xl[q] = *(const f4*)(xtp + q * 4);
#pragma unroll
        for (int j = 0; j < 4; j++) {
            uint4 o;
            o.x = pack2(xl[2 * j][0], xl[2 * j][1]);
            o.y = pack2(xl[2 * j][2], xl[2 * j][3]);
            o.z = pack2(xl[2 * j + 1][0], xl[2 * j + 1][1]);
            o.w = pack2(xl[2 * j + 1][2], xl[2 * j + 1][3]);
            *(uint4*)&sX0[sxo + j * 8] = o;
        }
    }
    __syncthreads();

#pragma unroll 1
    for (int cc = 0; cc < 8; cc++) {
        const short* cur = (cc & 1) ? sX1 : sX0;
        short*       nxt = (cc & 1) ? sX0 : sX1;

        // issue next-chunk x loads first: they age under this chunk's compute
        f4 xl[8];
        if (cc < 7) {
#pragma unroll
            for (int q = 0; q < 8; q++)
                xl[q] = *(const f4*)(xtp + (cc + 1) * 256 + q * 4);
        }

        // 8 K-steps, no synchronization inside
#pragma unroll
        for (int s = 0; s < 8; s++) {
            const short* sb = cur + s * 2560;
            bf16x8 a0 = *(const bf16x8*)&sb[(l15)      * 40 + quad * 8];
            bf16x8 a1 = *(const bf16x8*)&sb[(16 + l15) * 40 + quad * 8];
            bf16x8 a2 = *(const bf16x8*)&sb[(32 + l15) * 40 + quad * 8];
            bf16x8 a3 = *(const bf16x8*)&sb[(48 + l15) * 40 + quad * 8];
            const size_t kb = (size_t)(cc * 8 + s);
            bf16x8 wu0 = *(const bf16x8*)(wp + kb * 8192);
            bf16x8 wu1 = *(const bf16x8*)(wp + kb * 8192 + 512);
            acc[0][0] = __builtin_amdgcn_mfma_f32_16x16x32_bf16(a0, wu0, acc[0][0], 0, 0, 0);
            acc[0][1] = __builtin_amdgcn_mfma_f32_16x16x32_bf16(a0, wu1, acc[0][1], 0, 0, 0);
            acc[1][0] = __builtin_amdgcn_mfma_f32_16x16x32_bf16(a1, wu0, acc[1][0], 0, 0, 0);
            acc[1][1] = __builtin_amdgcn_mfma_f32_16x16x32_bf16(a1, wu1, acc[1][1], 0, 0, 0);
            acc[2][0] = __builtin_amdgcn_mfma_f32_16x16x32_bf16(a2, wu0, acc[2][0], 0, 0, 0);
            acc[2][1] = __builtin_amdgcn_mfma_f32_16x16x32_bf16(a2, wu1, acc[2][1], 0, 0, 0);
            acc[3][0] = __builtin_amdgcn_mfma_f32_16x16x32_bf16(a3, wu0, acc[3][0], 0, 0, 0);
            acc[3][1] = __builtin_amdgcn_mfma_f32_16x16x32_bf16(a3, wu1, acc[3][1], 0, 0, 0);
        }

        // pack + write next chunk into the other buffer
        if (cc < 7) {
#pragma unroll
            for (int j = 0; j < 4; j++) {
                uint4 o;
                o.x = pack2(xl[2 * j][0], xl[2 * j][1]);
                o.y = pack2(xl[2 * j][2], xl[2 * j][3]);
                o.z = pack2(xl[2 * j + 1][0], xl[2 * j + 1][1]);
                o.w = pack2(xl[2 * j + 1][2], xl[2 * j + 1][3]);
                *(uint4*)&nxt[sxo + j * 8] = o;
            }
        }
        __syncthreads();
    }

    // ---- layer-1 epilogue: bias + clip01 -> sh1 (aliases buffer 0) ----
#pragma unroll
    for (int j = 0; j < 2; j++) {
        int col = w * 32 + j * 16 + l15;
        float bias = b1[bkt * NH1 + col];
#pragma unroll
        for (int f = 0; f < 4; f++)
#pragma unroll
            for (int r = 0; r < 4; r++) {
                int row = f * 16 + quad * 4 + r;
                sh1[row * 264 + col] = (short)f2bf(clamp01(acc[f][j][r] + bias));
            }
    }
    __syncthreads();

    // ---- layer 2: wave w -> h2 rows (w&3)*16..+15, cols (w>>2)*32..+31 ----
    const int rw = w & 3, ch2 = w >> 2;
    f32x4 c2[2];
    c2[0] = (f32x4)0.0f; c2[1] = (f32x4)0.0f;
    const short* w2p = W2f + (size_t)bkt * 16384 + lane * 8;
#pragma unroll
    for (int kb2 = 0; kb2 < 8; kb2++) {
        bf16x8 a2 = *(const bf16x8*)&sh1[(rw * 16 + l15) * 264 + kb2 * 32 + quad * 8];
#pragma unroll
        for (int j = 0; j < 2; j++) {
            bf16x8 bw = *(const bf16x8*)(w2p + (kb2 * 4 + ch2 * 2 + j) * 512);
            c2[j] = __builtin_amdgcn_mfma_f32_16x16x32_bf16(a2, bw, c2[j], 0, 0, 0);
        }
    }

    // ---- layer-2 epilogue + layer-3 partial dot ----
    float s[4] = {0, 0, 0, 0};
#pragma unroll
    for (int j = 0; j < 2; j++) {
        int n2 = (ch2 * 2 + j) * 16 + l15;
        float bias2 = b2[bkt * NH2 + n2];
        float w3v   = W3[bkt * NH2 + n2];
#pragma unroll
        for (int r = 0; r < 4; r++)
            s[r] += clamp01(c2[j][r] + bias2) * w3v;
    }
#pragma unroll
    for (int r = 0; r < 4; r++) {
        float pp = s[r];
        pp += __shfl_xor(pp, 1); pp += __shfl_xor(pp, 2);
        pp += __shfl_xor(pp, 4); pp += __shfl_xor(pp, 8);
        if (l15 == 0) sPart[ch2 * TS + rw * 16 + quad * 4 + r] = pp;
    }
    __syncthreads();
    if (t < TS && base + t < cnt)
        out[order[off + base + t]] = sPart[t] + sPart[TS + t] + b3[bkt];
}

// ============================ naive fallback ============================

__global__ void naive_mlp(const float* __restrict__ x, const int* __restrict__ idx,
                          const float* __restrict__ W1, const float* __restrict__ b1,
                          const float* __restrict__ W2, const float* __restrict__ b2,
                          const float* __restrict__ W3, const float* __restrict__ b3,
                          float* __restrict__ out)
{
    int i = blockIdx.x;
    int b = idx[i];
    __shared__ float sx[INSZ];
    __shared__ float sh1n[NH1];
    __shared__ float sh2n[NH2];
    for (int t = threadIdx.x; t < INSZ; t += 256) sx[t] = x[(size_t)i * INSZ + t];
    __syncthreads();
    int j = threadIdx.x;
    {
        const float* wr = W1 + (size_t)(b * NH1 + j) * INSZ;
        float acc = b1[b * NH1 + j];
        for (int k = 0; k < INSZ; k++) acc += sx[k] * wr[k];
        sh1n[j] = fminf(fmaxf(acc, 0.f), 1.f);
    }
    __syncthreads();
    if (j < NH2) {
        const float* wr = W2 + (size_t)(b * NH2 + j) * NH1;
        float acc = b2[b * NH2 + j];
        for (int k = 0; k < NH1; k++) acc += sh1n[k] * wr[k];
        sh2n[j] = fminf(fmaxf(acc, 0.f), 1.f);
    }
    __syncthreads();
    if (j == 0) {
        float acc = b3[b];
        for (int k = 0; k < NH2; k++) acc += sh2n[k] * W3[b * NH2 + k];
        out[i] = acc;
    }
}

extern "C" void kernel_launch(void* const* d_in, const int* in_sizes, int n_in,
                              void* d_out, int out_size, void* d_ws, size_t ws_size,
                              hipStream_t stream) {
    const float* x  = (const float*)d_in[0];
    const int* bidx = (const int*)d_in[1];
    const float* W1 = (const float*)d_in[2];
    const float* b1 = (const float*)d_in[3];
    const float* W2 = (const float*)d_in[4];
    const float* b2 = (const float*)d_in[5];
    const float* W3 = (const float*)d_in[6];
    const float* b3 = (const float*)d_in[7];
    float* out = (float*)d_out;

    if (ws_size >= (size_t)WS_NEED) {
        char* ws = (char*)d_ws;
        int*   meta  = (int*)(ws + META_OFF);
        int*   order = (int*)(ws + ORDER_OFF);
        uint4* W1f   = (uint4*)(ws + W1F_OFF);
        uint4* W2f   = (uint4*)(ws + W2F_OFF);

        k_countscan<<<1, 1024, 0, stream>>>(bidx, meta);
        k_scatter<<<BATCH / 1024, 1024, 0, stream>>>(bidx, meta, order);
        k_pack<<<(W1F_U4 + W2F_U4) / 256, 256, 0, stream>>>(W1, W2, W1f, W2f);
        fused_v11<<<GRIDX, 512, 0, stream>>>(x, meta, order,
                                             (const short*)W1f, (const short*)W2f,
                                             b1, b2, W3, b3, out);
    } else {
        naive_mlp<<<BATCH, 256, 0, stream>>>(x, bidx, W1, b1, W2, b2, W3, b3, out);
    }
}